// Round 9
// baseline (246.799 us; speedup 1.0000x reference)
//
#include <hip/hip_runtime.h>
#include <hip/hip_bf16.h>
#include <cstdint>

using bf16 = __hip_bfloat16;
typedef __attribute__((ext_vector_type(8))) short bf16x8;
typedef __attribute__((ext_vector_type(4))) float f32x4;

// problem constants: DIM=1024, HEADS=16, HD=64, B=2, S=2048
// workspace layout (bf16 element offsets); total 24M elems = 48 MB
constexpr size_t OFF_WQT = 0;                 // 1M each, transposed bf16 weights
constexpr size_t OFF_WKT = (size_t)1 << 20;
constexpr size_t OFF_WVT = (size_t)2 << 20;
constexpr size_t OFF_WOT = (size_t)3 << 20;
constexpr size_t OFF_HB  = (size_t)4 << 20;  // H as bf16 [4096][1024]
constexpr size_t OFF_Q   = (size_t)8 << 20;  // [b*16+h][s][d]
constexpr size_t OFF_K   = (size_t)12 << 20; // [b*16+h][s][d]
constexpr size_t OFF_VT  = (size_t)16 << 20; // [b*16+h][d][s]
constexpr size_t OFF_ATT = (size_t)20 << 20; // [b*2048+s][h*64+d]

__device__ __forceinline__ void gload_lds16(const void* g, void* l) {
  auto gp = reinterpret_cast<const __attribute__((address_space(1))) void*>(
      reinterpret_cast<uintptr_t>(g));
  auto lp = reinterpret_cast<__attribute__((address_space(3))) void*>(
      static_cast<uint32_t>(reinterpret_cast<uintptr_t>(l)));
  __builtin_amdgcn_global_load_lds(gp, lp, 16, 0, 0);
}

__device__ __forceinline__ short f2b(float x) {
  return (short)__builtin_bit_cast(unsigned short, __float2bfloat16(x));
}

// ---------------- H: f32 -> bf16, 8 elems/thread ----------------
__global__ __launch_bounds__(256) void cvt_h(const float* __restrict__ in,
                                             bf16* __restrict__ out) {
  const int i = blockIdx.x * 256 + threadIdx.x;  // 4M/8 = 512K threads
  const f32x4 a = *(const f32x4*)(in + (size_t)i * 8);
  const f32x4 b = *(const f32x4*)(in + (size_t)i * 8 + 4);
  bf16x8 v;
  v[0] = f2b(a[0]); v[1] = f2b(a[1]); v[2] = f2b(a[2]); v[3] = f2b(a[3]);
  v[4] = f2b(b[0]); v[5] = f2b(b[1]); v[6] = f2b(b[2]); v[7] = f2b(b[3]);
  *(bf16x8*)((short*)out + (size_t)i * 8) = v;
}

// ---------------- weight transpose + cvt: WT[n][k] = bf16(W[k][n]) ----------------
__global__ __launch_bounds__(256) void transpose_w(
    const float* __restrict__ w0, const float* __restrict__ w1,
    const float* __restrict__ w2, const float* __restrict__ w3,
    bf16* __restrict__ ws) {
  __shared__ float t[64][65];
  const float* src = (blockIdx.z == 0) ? w0 : (blockIdx.z == 1) ? w1
                   : (blockIdx.z == 2) ? w2 : w3;
  bf16* dst = ws + ((size_t)blockIdx.z << 20);
  const int r0 = blockIdx.y * 64, c0 = blockIdx.x * 64;
  for (int i = threadIdx.x; i < 4096; i += 256) {
    const int r = i >> 6, c = i & 63;
    t[r][c] = src[(size_t)(r0 + r) * 1024 + c0 + c];
  }
  __syncthreads();
  for (int i = threadIdx.x; i < 4096; i += 256) {
    const int r = i >> 6, c = i & 63;
    dst[(size_t)(c0 + r) * 1024 + r0 + c] = __float2bfloat16(t[c][r]);
  }
}

// ---------------- GEMM: C = A(MxK) * Bt(NxK)^T, K=1024, tiles 128x128x64 ----------------
// MODE 0 (fused QKV): A=Hb; z=0: Bt=WqT, C->Q [bh][s][d] scaled 0.125*log2e
//                            z=1: Bt=WkT, C->K [bh][s][d]
//                            z=2: Bt=WvT, C->V transposed [bh][d][s]
// MODE 2: A=att, Bt0=WoT, C0-> d_out [m][n] (FLOAT32 - reference output dtype)
template <int MODE>
__global__ __launch_bounds__(256) void gemm_k(
    const bf16* __restrict__ A, const bf16* __restrict__ Bt0,
    const bf16* __restrict__ Bt1, const bf16* __restrict__ Bt2,
    void* __restrict__ C0, void* __restrict__ C1, void* __restrict__ C2) {
  __shared__ __attribute__((aligned(16))) bf16 As[128 * 64];
  __shared__ __attribute__((aligned(16))) bf16 Bs[128 * 64];
  const int tid = threadIdx.x;
  const int wv = tid >> 6, ln = tid & 63;
  const int m0 = blockIdx.y * 128, n0 = blockIdx.x * 128;
  const int z = blockIdx.z;
  const bf16* Bt = (MODE != 0 || z == 0) ? Bt0 : (z == 1) ? Bt1 : Bt2;
  void* C = (MODE != 0 || z == 0) ? C0 : (z == 1) ? C1 : C2;
  const int wm = (wv >> 1) * 64, wn = (wv & 1) * 64;
  const int srow = ln >> 3, scol = (ln & 7) * 8;
  f32x4 acc[4][4] = {};

  for (int kt = 0; kt < 16; ++kt) {
    __syncthreads();  // previous tile fully consumed
    const int kb = kt * 64;
#pragma unroll
    for (int j = 0; j < 4; ++j) {
      const int rr = (wv * 4 + j) * 8 + srow;
      gload_lds16(A  + (size_t)(m0 + rr) * 1024 + kb + scol, As + (size_t)(wv * 4 + j) * 512);
      gload_lds16(Bt + (size_t)(n0 + rr) * 1024 + kb + scol, Bs + (size_t)(wv * 4 + j) * 512);
    }
    __syncthreads();  // compiler drains vmcnt(0) before barrier
#pragma unroll
    for (int ks = 0; ks < 2; ++ks) {
      bf16x8 af[4], bfr[4];
#pragma unroll
      for (int i = 0; i < 4; ++i) {
        af[i]  = *(const bf16x8*)(As + (wm + i * 16 + (ln & 15)) * 64 + ks * 32 + (ln >> 4) * 8);
        bfr[i] = *(const bf16x8*)(Bs + (wn + i * 16 + (ln & 15)) * 64 + ks * 32 + (ln >> 4) * 8);
      }
#pragma unroll
      for (int i = 0; i < 4; ++i)
#pragma unroll
        for (int j = 0; j < 4; ++j)
          acc[i][j] = __builtin_amdgcn_mfma_f32_16x16x32_bf16(af[i], bfr[j], acc[i][j], 0, 0, 0);
    }
  }

  // Q scale folds softmax 1/8 and log2(e) so attention can use exp2 directly
  const float scl = (MODE == 0 && z == 0) ? 0.125f * 1.44269504088896f : 1.0f;
#pragma unroll
  for (int i = 0; i < 4; ++i)
#pragma unroll
    for (int j = 0; j < 4; ++j)
#pragma unroll
      for (int r = 0; r < 4; ++r) {
        const int m = m0 + wm + i * 16 + (ln >> 4) * 4 + r;
        const int n = n0 + wn + j * 16 + (ln & 15);
        const float v = acc[i][j][r] * scl;
        if (MODE == 0) {
          size_t idx;
          if (z == 2) {
            // V transposed: vt[b][h*64+d][s], n = h*64+d, s = m&2047, b = m>>11
            idx = ((size_t)(m >> 11) << 21) + (size_t)n * 2048 + (m & 2047);
          } else {
            // [b*16+h][s][d]: b=m>>11, s=m&2047, h=n>>6, d=n&63
            idx = ((size_t)((m >> 11) * 16 + (n >> 6)) << 17) + (size_t)(m & 2047) * 64 + (n & 63);
          }
          ((bf16*)C)[idx] = __float2bfloat16(v);
        } else {
          // final output: reference dtype is float32
          ((float*)C)[(size_t)m * 1024 + n] = v;
        }
      }
}

// ---------------- attention: per (b,h), 128 q-rows per block, 8 waves x 16 rows ----------------
// K/V tiles double-buffered in LDS, staged once per block (shared by 8 waves).
// LDS tiles use both-sides XOR swizzle: linear gload_lds dest + pre-swizzled global
// source + swizzled ds_read (byte ^= (row&7)<<4) -> conflict-free stride-128B reads.
__global__ __launch_bounds__(512) void attn_k(
    const bf16* __restrict__ qg, const bf16* __restrict__ kg,
    const bf16* __restrict__ vtg, const int* __restrict__ mask,
    bf16* __restrict__ att) {
  __shared__ __attribute__((aligned(16))) bf16 Ks[2][4096];  // [64 kv][64 d] swizzled
  __shared__ __attribute__((aligned(16))) bf16 Vs[2][4096];  // [64 d][64 kv] swizzled
  __shared__ __attribute__((aligned(16))) short Ps[128 * 64]; // per-wave 16-row stripes
  const int tid = threadIdx.x, wv = tid >> 6, ln = tid & 63;
  const int bh = blockIdx.y, b = bh >> 4, h = bh & 15;
  const int q0 = blockIdx.x * 128;
  const bf16* qh  = qg  + (size_t)bh * (2048 * 64);
  const bf16* kh  = kg  + (size_t)bh * (2048 * 64);
  const bf16* vth = vtg + (size_t)bh * (64 * 2048);
  const int* mb = mask + b * 2048;
  const int g = ln >> 4, c = ln & 15;
  // staging: thread t fills LDS byte t*16; row=t>>3, logical chunk=(t&7)^(row&7)
  const int srow = tid >> 3;
  const int slch = (tid & 7) ^ (srow & 7);
  const int xr = (c & 7) << 4;  // read-side XOR (row & 7)<<4, row = *16 + c

  // hoist Q fragments (A-layout: row=c, k-chunk=g); 16 q-rows per wave
  bf16x8 qf[2];
#pragma unroll
  for (int ks = 0; ks < 2; ++ks)
    qf[ks] = *(const bf16x8*)(qh + (size_t)(q0 + wv * 16 + c) * 64 + ks * 32 + g * 8);

  // constant ones B-fragment: column 0 = 1 -> row-sum of P via MFMA
  bf16x8 onesf;
#pragma unroll
  for (int i = 0; i < 8; ++i) onesf[i] = (c == 0) ? (short)0x3F80 : (short)0;

  f32x4 o[4] = {};
  f32x4 ol = {};

  // prologue: stage tile 0
  gload_lds16(kh + (size_t)srow * 64 + slch * 8, (char*)&Ks[0][0] + wv * 1024);
  gload_lds16(vth + (size_t)srow * 2048 + slch * 8, (char*)&Vs[0][0] + wv * 1024);
  __syncthreads();

  for (int kt = 0; kt < 32; ++kt) {
    const int cur = kt & 1;
    if (kt < 31) {  // prefetch next tile into the other buffer
      gload_lds16(kh + (size_t)((kt + 1) * 64 + srow) * 64 + slch * 8,
                  (char*)&Ks[cur ^ 1][0] + wv * 1024);
      gload_lds16(vth + (size_t)srow * 2048 + (kt + 1) * 64 + slch * 8,
                  (char*)&Vs[cur ^ 1][0] + wv * 1024);
    }
    // ---- scores = Q K^T from staged LDS ----
    f32x4 sf[4] = {};
    __builtin_amdgcn_s_setprio(1);
#pragma unroll
    for (int ks = 0; ks < 2; ++ks) {
      bf16x8 kf[4];
#pragma unroll
      for (int nk = 0; nk < 4; ++nk)
        kf[nk] = *(const bf16x8*)((const char*)&Ks[cur][0] + (nk * 16 + c) * 128 +
                                  ((ks * 64 + g * 16) ^ xr));
#pragma unroll
      for (int nk = 0; nk < 4; ++nk)
        sf[nk] = __builtin_amdgcn_mfma_f32_16x16x32_bf16(qf[ks], kf[nk], sf[nk], 0, 0, 0);
    }
    __builtin_amdgcn_s_setprio(0);
    // ---- P = exp2(min(s,43)) (log2e folded into Q scale), masked -> 0 ----
#pragma unroll
    for (int nk = 0; nk < 4; ++nk) {
      const bool live = (mb[kt * 64 + nk * 16 + c] != 0);
#pragma unroll
      for (int r = 0; r < 4; ++r) {
        const float p = live ? __builtin_amdgcn_exp2f(fminf(sf[nk][r], 43.0f)) : 0.0f;
        const int qr = wv * 16 + g * 4 + r;
        *(short*)((char*)Ps + qr * 128 + (((nk * 16 + c) * 2) ^ ((qr & 7) << 4))) = f2b(p);
      }
    }
    asm volatile("" ::: "memory");  // order P-writes before P-reads (wave-private stripe)
    // ---- O += P V ; denominator accumulated as ones-column MFMA ----
    __builtin_amdgcn_s_setprio(1);
#pragma unroll
    for (int ks = 0; ks < 2; ++ks) {
      const int qr = wv * 16 + c;
      const bf16x8 pf =
          *(const bf16x8*)((const char*)Ps + qr * 128 + ((ks * 64 + g * 16) ^ ((qr & 7) << 4)));
      bf16x8 vf[4];
#pragma unroll
      for (int nd = 0; nd < 4; ++nd)
        vf[nd] = *(const bf16x8*)((const char*)&Vs[cur][0] + (nd * 16 + c) * 128 +
                                  ((ks * 64 + g * 16) ^ xr));
#pragma unroll
      for (int nd = 0; nd < 4; ++nd)
        o[nd] = __builtin_amdgcn_mfma_f32_16x16x32_bf16(pf, vf[nd], o[nd], 0, 0, 0);
      ol = __builtin_amdgcn_mfma_f32_16x16x32_bf16(pf, onesf, ol, 0, 0, 0);
    }
    __builtin_amdgcn_s_setprio(0);
    asm volatile("" ::: "memory");  // order P-reads before next tile's P-writes
    __syncthreads();  // drains vmcnt(0): prefetch landed; all waves done with cur
  }

  // normalize and store att[b*2048+q][h*64+d]
#pragma unroll
  for (int r = 0; r < 4; ++r) {
    const float lsum = __shfl(ol[r], ln & 48, 64);  // broadcast col-0 lane of the group
    const float inv = 1.0f / fmaxf(lsum, 1e-30f);
    const int qr = q0 + wv * 16 + g * 4 + r;
#pragma unroll
    for (int nd = 0; nd < 4; ++nd)
      att[(size_t)(b * 2048 + qr) * 1024 + h * 64 + nd * 16 + c] =
          __float2bfloat16(o[nd][r] * inv);
  }
}

extern "C" void kernel_launch(void* const* d_in, const int* in_sizes, int n_in,
                              void* d_out, int out_size, void* d_ws, size_t ws_size,
                              hipStream_t stream) {
  (void)in_sizes; (void)n_in; (void)out_size; (void)ws_size;
  const float* H    = (const float*)d_in[0];   // inputs are float32 per reference
  const int*   mask = (const int*)d_in[1];
  const float* Wq   = (const float*)d_in[2];
  const float* Wk   = (const float*)d_in[3];
  const float* Wv   = (const float*)d_in[4];
  const float* Wo   = (const float*)d_in[5];
  bf16* ws   = (bf16*)d_ws;
  bf16* wqT  = ws + OFF_WQT;
  bf16* wkT  = ws + OFF_WKT;
  bf16* wvT  = ws + OFF_WVT;
  bf16* woT  = ws + OFF_WOT;
  bf16* hb   = ws + OFF_HB;
  bf16* qws  = ws + OFF_Q;
  bf16* kws  = ws + OFF_K;
  bf16* vtws = ws + OFF_VT;
  bf16* attw = ws + OFF_ATT;

  transpose_w<<<dim3(16, 16, 4), 256, 0, stream>>>(Wq, Wk, Wv, Wo, ws);
  cvt_h<<<dim3(2048), 256, 0, stream>>>(H, hb);   // 4M elems, 8/thread
  // fused QKV projection: z=0 Q (scaled), z=1 K, z=2 V (transposed write)
  gemm_k<0><<<dim3(8, 32, 3), 256, 0, stream>>>(hb, wqT, wkT, wvT, qws, kws, vtws);
  // attention: 128 q-rows per block, 8 waves, LDS-staged K/V
  attn_k<<<dim3(16, 32), 512, 0, stream>>>(qws, kws, vtws, mask, attw);
  // output projection -> float32 d_out
  gemm_k<2><<<dim3(8, 32, 1), 256, 0, stream>>>(attw, woT, nullptr, nullptr, d_out, nullptr, nullptr);
}

// Round 10
// 232.489 us; speedup vs baseline: 1.0615x; 1.0615x over previous
//
#include <hip/hip_runtime.h>
#include <hip/hip_bf16.h>
#include <cstdint>

using bf16 = __hip_bfloat16;
typedef __attribute__((ext_vector_type(8))) short bf16x8;
typedef __attribute__((ext_vector_type(4))) float f32x4;

// problem constants: DIM=1024, HEADS=16, HD=64, B=2, S=2048
// workspace layout (bf16 element offsets); total 24M elems = 48 MB
constexpr size_t OFF_WQT = 0;                 // 1M each, transposed bf16 weights
constexpr size_t OFF_WKT = (size_t)1 << 20;
constexpr size_t OFF_WVT = (size_t)2 << 20;
constexpr size_t OFF_WOT = (size_t)3 << 20;
constexpr size_t OFF_HB  = (size_t)4 << 20;  // H as bf16 [4096][1024]
constexpr size_t OFF_Q   = (size_t)8 << 20;  // [b*16+h][s][d]
constexpr size_t OFF_K   = (size_t)12 << 20; // [b*16+h][s][d]
constexpr size_t OFF_VT  = (size_t)16 << 20; // [b*16+h][d][s]
constexpr size_t OFF_ATT = (size_t)20 << 20; // [b*2048+s][h*64+d]

__device__ __forceinline__ void gload_lds16(const void* g, void* l) {
  auto gp = reinterpret_cast<const __attribute__((address_space(1))) void*>(
      reinterpret_cast<uintptr_t>(g));
  auto lp = reinterpret_cast<__attribute__((address_space(3))) void*>(
      static_cast<uint32_t>(reinterpret_cast<uintptr_t>(l)));
  __builtin_amdgcn_global_load_lds(gp, lp, 16, 0, 0);
}

__device__ __forceinline__ short f2b(float x) {
  return (short)__builtin_bit_cast(unsigned short, __float2bfloat16(x));
}

// ---------------- H: f32 -> bf16, 8 elems/thread ----------------
__global__ __launch_bounds__(256) void cvt_h(const float* __restrict__ in,
                                             bf16* __restrict__ out) {
  const int i = blockIdx.x * 256 + threadIdx.x;  // 4M/8 = 512K threads
  const f32x4 a = *(const f32x4*)(in + (size_t)i * 8);
  const f32x4 b = *(const f32x4*)(in + (size_t)i * 8 + 4);
  bf16x8 v;
  v[0] = f2b(a[0]); v[1] = f2b(a[1]); v[2] = f2b(a[2]); v[3] = f2b(a[3]);
  v[4] = f2b(b[0]); v[5] = f2b(b[1]); v[6] = f2b(b[2]); v[7] = f2b(b[3]);
  *(bf16x8*)((short*)out + (size_t)i * 8) = v;
}

// ---------------- weight transpose + cvt: WT[n][k] = bf16(W[k][n]) ----------------
__global__ __launch_bounds__(256) void transpose_w(
    const float* __restrict__ w0, const float* __restrict__ w1,
    const float* __restrict__ w2, const float* __restrict__ w3,
    bf16* __restrict__ ws) {
  __shared__ float t[64][65];
  const float* src = (blockIdx.z == 0) ? w0 : (blockIdx.z == 1) ? w1
                   : (blockIdx.z == 2) ? w2 : w3;
  bf16* dst = ws + ((size_t)blockIdx.z << 20);
  const int r0 = blockIdx.y * 64, c0 = blockIdx.x * 64;
  for (int i = threadIdx.x; i < 4096; i += 256) {
    const int r = i >> 6, c = i & 63;
    t[r][c] = src[(size_t)(r0 + r) * 1024 + c0 + c];
  }
  __syncthreads();
  for (int i = threadIdx.x; i < 4096; i += 256) {
    const int r = i >> 6, c = i & 63;
    dst[(size_t)(c0 + r) * 1024 + r0 + c] = __float2bfloat16(t[c][r]);
  }
}

// ---------------- GEMM: C = A(MxK) * Bt(NxK)^T, K=1024 ----------------
// MODE 0 (fused QKV, BM=128 BN=128, grid 8x32x3):
//   z=0: Bt=WqT, C->Q [bh][s][d] scaled 0.125*log2e
//   z=1: Bt=WkT, C->K [bh][s][d]
//   z=2: Bt=WvT, SWAPPED MFMA operands -> acc holds C^T tile -> coalesced
//        write V transposed: vt[b][h*64+d][s]
// MODE 2 (output proj, BM=128 BN=64, grid 16x32): A=att, Bt0=WoT,
//   C0-> d_out [m][n] float32 (reference output dtype)
template <int MODE>
__global__ __launch_bounds__(256) void gemm_k(
    const bf16* __restrict__ A, const bf16* __restrict__ Bt0,
    const bf16* __restrict__ Bt1, const bf16* __restrict__ Bt2,
    void* __restrict__ C0, void* __restrict__ C1, void* __restrict__ C2) {
  constexpr int BN = (MODE == 2) ? 64 : 128;   // block N-tile
  constexpr int NJ = BN / 32;                  // per-wave 16-col tiles (4 or 2)
  constexpr int BJ = BN / 32;                  // B-staging loads per thread
  __shared__ __attribute__((aligned(16))) bf16 As[128 * 64];
  __shared__ __attribute__((aligned(16))) bf16 Bs[BN * 64];
  const int tid = threadIdx.x;
  const int wv = tid >> 6, ln = tid & 63;
  const int m0 = blockIdx.y * 128, n0 = blockIdx.x * BN;
  const int z = blockIdx.z;
  const bf16* Bt = (MODE != 0 || z == 0) ? Bt0 : (z == 1) ? Bt1 : Bt2;
  void* C = (MODE != 0 || z == 0) ? C0 : (z == 1) ? C1 : C2;
  const int wm = (wv >> 1) * 64, wn = (wv & 1) * (BN / 2);
  const int srow = ln >> 3, scol = (ln & 7) * 8;
  const bool swapped = (MODE == 0) && (z == 2);
  f32x4 acc[4][NJ] = {};

  for (int kt = 0; kt < 16; ++kt) {
    __syncthreads();  // previous tile fully consumed
    const int kb = kt * 64;
#pragma unroll
    for (int j = 0; j < 4; ++j) {
      const int rr = (wv * 4 + j) * 8 + srow;
      gload_lds16(A + (size_t)(m0 + rr) * 1024 + kb + scol, As + (size_t)(wv * 4 + j) * 512);
    }
#pragma unroll
    for (int j = 0; j < BJ; ++j) {
      const int rr = (wv * BJ + j) * 8 + srow;
      gload_lds16(Bt + (size_t)(n0 + rr) * 1024 + kb + scol, Bs + (size_t)(wv * BJ + j) * 512);
    }
    __syncthreads();  // compiler drains vmcnt(0) before barrier
#pragma unroll
    for (int ks = 0; ks < 2; ++ks) {
      bf16x8 af[4], bfr[NJ];
#pragma unroll
      for (int i = 0; i < 4; ++i)
        af[i] = *(const bf16x8*)(As + (wm + i * 16 + (ln & 15)) * 64 + ks * 32 + (ln >> 4) * 8);
#pragma unroll
      for (int j = 0; j < NJ; ++j)
        bfr[j] = *(const bf16x8*)(Bs + (wn + j * 16 + (ln & 15)) * 64 + ks * 32 + (ln >> 4) * 8);
      if (!swapped) {
#pragma unroll
        for (int i = 0; i < 4; ++i)
#pragma unroll
          for (int j = 0; j < NJ; ++j)
            acc[i][j] = __builtin_amdgcn_mfma_f32_16x16x32_bf16(af[i], bfr[j], acc[i][j], 0, 0, 0);
      } else {
        // swapped operands: acc[i][j] = (Bt-tile j) x (A-tile i)^T -> rows=n, cols=m
#pragma unroll
        for (int i = 0; i < 4; ++i)
#pragma unroll
          for (int j = 0; j < NJ; ++j)
            acc[i][j] = __builtin_amdgcn_mfma_f32_16x16x32_bf16(bfr[j], af[i], acc[i][j], 0, 0, 0);
      }
    }
  }

  // Q scale folds softmax 1/8 and log2(e) so attention can use exp2 directly
  const float scl = (MODE == 0 && z == 0) ? 0.125f * 1.44269504088896f : 1.0f;
#pragma unroll
  for (int i = 0; i < 4; ++i)
#pragma unroll
    for (int j = 0; j < NJ; ++j)
#pragma unroll
      for (int r = 0; r < 4; ++r) {
        const float v = acc[i][j][r] * scl;
        if (MODE == 0 && z == 2) {
          // transposed tile: row = n (= h*64+d), col = m (= b*2048+s), coalesced in s
          const int nrow = n0 + wn + j * 16 + (ln >> 4) * 4 + r;
          const int mcol = m0 + wm + i * 16 + (ln & 15);
          const size_t idx = ((size_t)(mcol >> 11) << 21) + (size_t)nrow * 2048 + (mcol & 2047);
          ((bf16*)C)[idx] = __float2bfloat16(v);
        } else {
          const int m = m0 + wm + i * 16 + (ln >> 4) * 4 + r;
          const int n = n0 + wn + j * 16 + (ln & 15);
          if (MODE == 0) {
            // [b*16+h][s][d]: b=m>>11, s=m&2047, h=n>>6, d=n&63
            const size_t idx =
                ((size_t)((m >> 11) * 16 + (n >> 6)) << 17) + (size_t)(m & 2047) * 64 + (n & 63);
            ((bf16*)C)[idx] = __float2bfloat16(v);
          } else {
            ((float*)C)[(size_t)m * 1024 + n] = v;  // final output: float32
          }
        }
      }
}

// ---------------- attention: per (b,h), 128 q-rows per block, 8 waves x 16 rows ----------------
// K/V tiles double-buffered in LDS, staged once per block (shared by 8 waves).
// LDS tiles use both-sides XOR swizzle: linear gload_lds dest + pre-swizzled global
// source + swizzled ds_read (byte ^= (row&7)<<4) -> conflict-free stride-128B reads.
__global__ __launch_bounds__(512) void attn_k(
    const bf16* __restrict__ qg, const bf16* __restrict__ kg,
    const bf16* __restrict__ vtg, const int* __restrict__ mask,
    bf16* __restrict__ att) {
  __shared__ __attribute__((aligned(16))) bf16 Ks[2][4096];  // [64 kv][64 d] swizzled
  __shared__ __attribute__((aligned(16))) bf16 Vs[2][4096];  // [64 d][64 kv] swizzled
  __shared__ __attribute__((aligned(16))) short Ps[128 * 64]; // per-wave 16-row stripes
  const int tid = threadIdx.x, wv = tid >> 6, ln = tid & 63;
  const int bh = blockIdx.y, b = bh >> 4, h = bh & 15;
  const int q0 = blockIdx.x * 128;
  const bf16* qh  = qg  + (size_t)bh * (2048 * 64);
  const bf16* kh  = kg  + (size_t)bh * (2048 * 64);
  const bf16* vth = vtg + (size_t)bh * (64 * 2048);
  const int* mb = mask + b * 2048;
  const int g = ln >> 4, c = ln & 15;
  // staging: thread t fills LDS byte t*16; row=t>>3, logical chunk=(t&7)^(row&7)
  const int srow = tid >> 3;
  const int slch = (tid & 7) ^ (srow & 7);
  const int xr = (c & 7) << 4;  // read-side XOR (row & 7)<<4, row = *16 + c

  // hoist Q fragments (A-layout: row=c, k-chunk=g); 16 q-rows per wave
  bf16x8 qf[2];
#pragma unroll
  for (int ks = 0; ks < 2; ++ks)
    qf[ks] = *(const bf16x8*)(qh + (size_t)(q0 + wv * 16 + c) * 64 + ks * 32 + g * 8);

  // constant ones B-fragment: column 0 = 1 -> row-sum of P via MFMA
  bf16x8 onesf;
#pragma unroll
  for (int i = 0; i < 8; ++i) onesf[i] = (c == 0) ? (short)0x3F80 : (short)0;

  f32x4 o[4] = {};
  f32x4 ol = {};

  // prologue: stage tile 0
  gload_lds16(kh + (size_t)srow * 64 + slch * 8, (char*)&Ks[0][0] + wv * 1024);
  gload_lds16(vth + (size_t)srow * 2048 + slch * 8, (char*)&Vs[0][0] + wv * 1024);
  __syncthreads();

  for (int kt = 0; kt < 32; ++kt) {
    const int cur = kt & 1;
    if (kt < 31) {  // prefetch next tile into the other buffer
      gload_lds16(kh + (size_t)((kt + 1) * 64 + srow) * 64 + slch * 8,
                  (char*)&Ks[cur ^ 1][0] + wv * 1024);
      gload_lds16(vth + (size_t)srow * 2048 + (kt + 1) * 64 + slch * 8,
                  (char*)&Vs[cur ^ 1][0] + wv * 1024);
    }
    // ---- scores = Q K^T from staged LDS ----
    f32x4 sf[4] = {};
#pragma unroll
    for (int ks = 0; ks < 2; ++ks) {
      bf16x8 kf[4];
#pragma unroll
      for (int nk = 0; nk < 4; ++nk)
        kf[nk] = *(const bf16x8*)((const char*)&Ks[cur][0] + (nk * 16 + c) * 128 +
                                  ((ks * 64 + g * 16) ^ xr));
#pragma unroll
      for (int nk = 0; nk < 4; ++nk)
        sf[nk] = __builtin_amdgcn_mfma_f32_16x16x32_bf16(qf[ks], kf[nk], sf[nk], 0, 0, 0);
    }
    // ---- P = exp2(min(s,43)) (log2e folded into Q scale), masked -> 0 ----
#pragma unroll
    for (int nk = 0; nk < 4; ++nk) {
      const bool live = (mb[kt * 64 + nk * 16 + c] != 0);
#pragma unroll
      for (int r = 0; r < 4; ++r) {
        const float p = live ? __builtin_amdgcn_exp2f(fminf(sf[nk][r], 43.0f)) : 0.0f;
        const int qr = wv * 16 + g * 4 + r;
        *(short*)((char*)Ps + qr * 128 + (((nk * 16 + c) * 2) ^ ((qr & 7) << 4))) = f2b(p);
      }
    }
    asm volatile("" ::: "memory");  // order P-writes before P-reads (wave-private stripe)
    // ---- O += P V ; denominator accumulated as ones-column MFMA ----
#pragma unroll
    for (int ks = 0; ks < 2; ++ks) {
      const int qr = wv * 16 + c;
      const bf16x8 pf =
          *(const bf16x8*)((const char*)Ps + qr * 128 + ((ks * 64 + g * 16) ^ ((qr & 7) << 4)));
      bf16x8 vf[4];
#pragma unroll
      for (int nd = 0; nd < 4; ++nd)
        vf[nd] = *(const bf16x8*)((const char*)&Vs[cur][0] + (nd * 16 + c) * 128 +
                                  ((ks * 64 + g * 16) ^ xr));
#pragma unroll
      for (int nd = 0; nd < 4; ++nd)
        o[nd] = __builtin_amdgcn_mfma_f32_16x16x32_bf16(pf, vf[nd], o[nd], 0, 0, 0);
      ol = __builtin_amdgcn_mfma_f32_16x16x32_bf16(pf, onesf, ol, 0, 0, 0);
    }
    asm volatile("" ::: "memory");  // order P-reads before next tile's P-writes
    __syncthreads();  // drains vmcnt(0): prefetch landed; all waves done with cur
  }

  // normalize and store att[b*2048+q][h*64+d]
#pragma unroll
  for (int r = 0; r < 4; ++r) {
    const float lsum = __shfl(ol[r], ln & 48, 64);  // broadcast col-0 lane of the group
    const float inv = 1.0f / fmaxf(lsum, 1e-30f);
    const int qr = q0 + wv * 16 + g * 4 + r;
#pragma unroll
    for (int nd = 0; nd < 4; ++nd)
      att[(size_t)(b * 2048 + qr) * 1024 + h * 64 + nd * 16 + c] =
          __float2bfloat16(o[nd][r] * inv);
  }
}

extern "C" void kernel_launch(void* const* d_in, const int* in_sizes, int n_in,
                              void* d_out, int out_size, void* d_ws, size_t ws_size,
                              hipStream_t stream) {
  (void)in_sizes; (void)n_in; (void)out_size; (void)ws_size;
  const float* H    = (const float*)d_in[0];   // inputs are float32 per reference
  const int*   mask = (const int*)d_in[1];
  const float* Wq   = (const float*)d_in[2];
  const float* Wk   = (const float*)d_in[3];
  const float* Wv   = (const float*)d_in[4];
  const float* Wo   = (const float*)d_in[5];
  bf16* ws   = (bf16*)d_ws;
  bf16* wqT  = ws + OFF_WQT;
  bf16* wkT  = ws + OFF_WKT;
  bf16* wvT  = ws + OFF_WVT;
  bf16* woT  = ws + OFF_WOT;
  bf16* hb   = ws + OFF_HB;
  bf16* qws  = ws + OFF_Q;
  bf16* kws  = ws + OFF_K;
  bf16* vtws = ws + OFF_VT;
  bf16* attw = ws + OFF_ATT;

  transpose_w<<<dim3(16, 16, 4), 256, 0, stream>>>(Wq, Wk, Wv, Wo, ws);
  cvt_h<<<dim3(2048), 256, 0, stream>>>(H, hb);   // 4M elems, 8/thread
  // fused QKV projection: z=0 Q (scaled), z=1 K, z=2 V (swapped-operand transposed write)
  gemm_k<0><<<dim3(8, 32, 3), 256, 0, stream>>>(hb, wqT, wkT, wvT, qws, kws, vtws);
  // attention: 128 q-rows per block, 8 waves, LDS-staged K/V
  attn_k<<<dim3(16, 32), 512, 0, stream>>>(qws, kws, vtws, mask, attw);
  // output projection (BM=128, BN=64 -> 512 blocks) -> float32 d_out
  gemm_k<2><<<dim3(16, 32), 256, 0, stream>>>(attw, woT, nullptr, nullptr, d_out, nullptr, nullptr);
}

// Round 12
// 226.897 us; speedup vs baseline: 1.0877x; 1.0246x over previous
//
#include <hip/hip_runtime.h>
#include <hip/hip_bf16.h>
#include <cstdint>

using bf16 = __hip_bfloat16;
typedef __attribute__((ext_vector_type(8))) short bf16x8;
typedef __attribute__((ext_vector_type(4))) float f32x4;

// problem constants: DIM=1024, HEADS=16, HD=64, B=2, S=2048
// workspace layout (bf16 element offsets); total 24M elems = 48 MB
constexpr size_t OFF_WQT = 0;                 // 1M each, transposed bf16 weights
constexpr size_t OFF_WKT = (size_t)1 << 20;
constexpr size_t OFF_WVT = (size_t)2 << 20;
constexpr size_t OFF_WOT = (size_t)3 << 20;
constexpr size_t OFF_HB  = (size_t)4 << 20;  // H as bf16 [4096][1024]
constexpr size_t OFF_Q   = (size_t)8 << 20;  // [b*16+h][s][d]
constexpr size_t OFF_K   = (size_t)12 << 20; // [b*16+h][s][d]
constexpr size_t OFF_VT  = (size_t)16 << 20; // [b*16+h][d][s]
constexpr size_t OFF_ATT = (size_t)20 << 20; // [b*2048+s][h*64+d]

__device__ __forceinline__ void gload_lds16(const void* g, void* l) {
  auto gp = reinterpret_cast<const __attribute__((address_space(1))) void*>(
      reinterpret_cast<uintptr_t>(g));
  auto lp = reinterpret_cast<__attribute__((address_space(3))) void*>(
      static_cast<uint32_t>(reinterpret_cast<uintptr_t>(l)));
  __builtin_amdgcn_global_load_lds(gp, lp, 16, 0, 0);
}

__device__ __forceinline__ short f2b(float x) {
  return (short)__builtin_bit_cast(unsigned short, __float2bfloat16(x));
}

// ---------------- prep: weight transpose+cvt (z<4) and H f32->bf16 (z==4) ----------------
__global__ __launch_bounds__(256) void prep_k(
    const float* __restrict__ w0, const float* __restrict__ w1,
    const float* __restrict__ w2, const float* __restrict__ w3,
    const float* __restrict__ H, bf16* __restrict__ ws, bf16* __restrict__ hb) {
  const int z = blockIdx.z;
  if (z < 4) {
    __shared__ float t[64][65];
    const float* src = (z == 0) ? w0 : (z == 1) ? w1 : (z == 2) ? w2 : w3;
    bf16* dst = ws + ((size_t)z << 20);
    const int r0 = blockIdx.y * 64, c0 = blockIdx.x * 64;
    for (int i = threadIdx.x; i < 4096; i += 256) {
      const int r = i >> 6, c = i & 63;
      t[r][c] = src[(size_t)(r0 + r) * 1024 + c0 + c];
    }
    __syncthreads();
    for (int i = threadIdx.x; i < 4096; i += 256) {
      const int r = i >> 6, c = i & 63;
      dst[(size_t)(c0 + r) * 1024 + r0 + c] = __float2bfloat16(t[c][r]);
    }
  } else {
    // H: 4M elems over 256 blocks -> 16384/block, 8 bf16x8 iters of 2048
    const size_t base = (size_t)(blockIdx.y * 16 + blockIdx.x) * 16384;
#pragma unroll
    for (int it = 0; it < 8; ++it) {
      const size_t e = base + (size_t)it * 2048 + threadIdx.x * 8;
      const f32x4 a = *(const f32x4*)(H + e);
      const f32x4 b = *(const f32x4*)(H + e + 4);
      bf16x8 v;
      v[0] = f2b(a[0]); v[1] = f2b(a[1]); v[2] = f2b(a[2]); v[3] = f2b(a[3]);
      v[4] = f2b(b[0]); v[5] = f2b(b[1]); v[6] = f2b(b[2]); v[7] = f2b(b[3]);
      *(bf16x8*)((short*)hb + e) = v;
    }
  }
}

// ---------------- GEMM: C = A(MxK) * Bt(NxK)^T, K=1024 ----------------
// MODE 0 (fused QKV, BM=128 BN=128, grid 8x32x3):
//   z=0: Bt=WqT, C->Q [bh][s][d] scaled 0.125*log2e
//   z=1: Bt=WkT, C->K [bh][s][d]
//   z=2: Bt=WvT, SWAPPED MFMA operands -> acc holds C^T tile -> coalesced
//        write V transposed: vt[b][h*64+d][s]
// MODE 2 (output proj, BM=128 BN=64, grid 16x32): A=att, Bt0=WoT,
//   C0-> d_out [m][n] float32 (reference output dtype)
template <int MODE>
__global__ __launch_bounds__(256) void gemm_k(
    const bf16* __restrict__ A, const bf16* __restrict__ Bt0,
    const bf16* __restrict__ Bt1, const bf16* __restrict__ Bt2,
    void* __restrict__ C0, void* __restrict__ C1, void* __restrict__ C2) {
  constexpr int BN = (MODE == 2) ? 64 : 128;   // block N-tile
  constexpr int NJ = BN / 32;                  // per-wave 16-col tiles (4 or 2)
  constexpr int BJ = BN / 32;                  // B-staging loads per thread
  __shared__ __attribute__((aligned(16))) bf16 As[128 * 64];
  __shared__ __attribute__((aligned(16))) bf16 Bs[BN * 64];
  const int tid = threadIdx.x;
  const int wv = tid >> 6, ln = tid & 63;
  const int m0 = blockIdx.y * 128, n0 = blockIdx.x * BN;
  const int z = blockIdx.z;
  const bf16* Bt = (MODE != 0 || z == 0) ? Bt0 : (z == 1) ? Bt1 : Bt2;
  void* C = (MODE != 0 || z == 0) ? C0 : (z == 1) ? C1 : C2;
  const int wm = (wv >> 1) * 64, wn = (wv & 1) * (BN / 2);
  const int srow = ln >> 3, scol = (ln & 7) * 8;
  const bool swapped = (MODE == 0) && (z == 2);
  f32x4 acc[4][NJ] = {};

  for (int kt = 0; kt < 16; ++kt) {
    __syncthreads();  // previous tile fully consumed
    const int kb = kt * 64;
#pragma unroll
    for (int j = 0; j < 4; ++j) {
      const int rr = (wv * 4 + j) * 8 + srow;
      gload_lds16(A + (size_t)(m0 + rr) * 1024 + kb + scol, As + (size_t)(wv * 4 + j) * 512);
    }
#pragma unroll
    for (int j = 0; j < BJ; ++j) {
      const int rr = (wv * BJ + j) * 8 + srow;
      gload_lds16(Bt + (size_t)(n0 + rr) * 1024 + kb + scol, Bs + (size_t)(wv * BJ + j) * 512);
    }
    __syncthreads();  // compiler drains vmcnt(0) before barrier
#pragma unroll
    for (int ks = 0; ks < 2; ++ks) {
      bf16x8 af[4], bfr[NJ];
#pragma unroll
      for (int i = 0; i < 4; ++i)
        af[i] = *(const bf16x8*)(As + (wm + i * 16 + (ln & 15)) * 64 + ks * 32 + (ln >> 4) * 8);
#pragma unroll
      for (int j = 0; j < NJ; ++j)
        bfr[j] = *(const bf16x8*)(Bs + (wn + j * 16 + (ln & 15)) * 64 + ks * 32 + (ln >> 4) * 8);
      if (!swapped) {
#pragma unroll
        for (int i = 0; i < 4; ++i)
#pragma unroll
          for (int j = 0; j < NJ; ++j)
            acc[i][j] = __builtin_amdgcn_mfma_f32_16x16x32_bf16(af[i], bfr[j], acc[i][j], 0, 0, 0);
      } else {
        // swapped operands: acc[i][j] = (Bt-tile j) x (A-tile i)^T -> rows=n, cols=m
#pragma unroll
        for (int i = 0; i < 4; ++i)
#pragma unroll
          for (int j = 0; j < NJ; ++j)
            acc[i][j] = __builtin_amdgcn_mfma_f32_16x16x32_bf16(bfr[j], af[i], acc[i][j], 0, 0, 0);
      }
    }
  }

  // Q scale folds softmax 1/8 and log2(e) so attention can use exp2 directly
  const float scl = (MODE == 0 && z == 0) ? 0.125f * 1.44269504088896f : 1.0f;
#pragma unroll
  for (int i = 0; i < 4; ++i)
#pragma unroll
    for (int j = 0; j < NJ; ++j)
#pragma unroll
      for (int r = 0; r < 4; ++r) {
        const float v = acc[i][j][r] * scl;
        if (MODE == 0 && z == 2) {
          // transposed tile: row = n (= h*64+d), col = m (= b*2048+s), coalesced in s
          const int nrow = n0 + wn + j * 16 + (ln >> 4) * 4 + r;
          const int mcol = m0 + wm + i * 16 + (ln & 15);
          const size_t idx = ((size_t)(mcol >> 11) << 21) + (size_t)nrow * 2048 + (mcol & 2047);
          ((bf16*)C)[idx] = __float2bfloat16(v);
        } else {
          const int m = m0 + wm + i * 16 + (ln >> 4) * 4 + r;
          const int n = n0 + wn + j * 16 + (ln & 15);
          if (MODE == 0) {
            // [b*16+h][s][d]: b=m>>11, s=m&2047, h=n>>6, d=n&63
            const size_t idx =
                ((size_t)((m >> 11) * 16 + (n >> 6)) << 17) + (size_t)(m & 2047) * 64 + (n & 63);
            ((bf16*)C)[idx] = __float2bfloat16(v);
          } else {
            ((float*)C)[(size_t)m * 1024 + n] = v;  // final output: float32
          }
        }
      }
}

// ---------------- attention: per (b,h), 128 q-rows per block, 8 waves x 16 rows ----------------
// SW-pipelined: QK(t+1) issued BEFORE exp(t) so QK MFMA latency hides under the exp
// VALU pass. K triple-buffered, V double-buffered in LDS (both-sides XOR swizzle,
// linear gload_lds dest + pre-swizzled global src + swizzled ds_read).
__global__ __launch_bounds__(512) void attn_k(
    const bf16* __restrict__ qg, const bf16* __restrict__ kg,
    const bf16* __restrict__ vtg, const int* __restrict__ mask,
    bf16* __restrict__ att) {
  __shared__ __attribute__((aligned(16))) bf16 Ks[3][4096];   // [64 kv][64 d] swizzled
  __shared__ __attribute__((aligned(16))) bf16 Vs[2][4096];   // [64 d][64 kv] swizzled
  __shared__ __attribute__((aligned(16))) short Ps[128 * 64]; // per-wave 16-row stripes
  const int tid = threadIdx.x, wv = tid >> 6, ln = tid & 63;
  const int bh = blockIdx.y, b = bh >> 4, h = bh & 15;
  const int q0 = blockIdx.x * 128;
  const bf16* qh  = qg  + (size_t)bh * (2048 * 64);
  const bf16* kh  = kg  + (size_t)bh * (2048 * 64);
  const bf16* vth = vtg + (size_t)bh * (64 * 2048);
  const int* mb = mask + b * 2048;
  const int g = ln >> 4, c = ln & 15;
  // staging: thread t fills LDS byte t*16; row=t>>3, logical chunk=(t&7)^(row&7)
  const int srow = tid >> 3;
  const int slch = (tid & 7) ^ (srow & 7);
  const int xr = (c & 7) << 4;  // read-side XOR (row & 7)<<4, row = *16 + c

  // hoist Q fragments (A-layout: row=c, k-chunk=g); 16 q-rows per wave
  bf16x8 qf[2];
#pragma unroll
  for (int ks = 0; ks < 2; ++ks)
    qf[ks] = *(const bf16x8*)(qh + (size_t)(q0 + wv * 16 + c) * 64 + ks * 32 + g * 8);

  // constant ones B-fragment: column 0 = 1 -> row-sum of P via MFMA
  bf16x8 onesf;
#pragma unroll
  for (int i = 0; i < 8; ++i) onesf[i] = (c == 0) ? (short)0x3F80 : (short)0;

  f32x4 o[4] = {};
  f32x4 ol = {};
  f32x4 sfA[4], sfB[4];

  auto qk = [&](const char* kbase, f32x4 (&SF)[4]) {
#pragma unroll
    for (int nk = 0; nk < 4; ++nk) SF[nk] = f32x4{0.f, 0.f, 0.f, 0.f};
#pragma unroll
    for (int ks = 0; ks < 2; ++ks) {
      bf16x8 kf[4];
#pragma unroll
      for (int nk = 0; nk < 4; ++nk)
        kf[nk] = *(const bf16x8*)(kbase + (nk * 16 + c) * 128 + ((ks * 64 + g * 16) ^ xr));
#pragma unroll
      for (int nk = 0; nk < 4; ++nk)
        SF[nk] = __builtin_amdgcn_mfma_f32_16x16x32_bf16(qf[ks], kf[nk], SF[nk], 0, 0, 0);
    }
  };
  auto expph = [&](int T, f32x4 (&SF)[4]) {
#pragma unroll
    for (int nk = 0; nk < 4; ++nk) {
      const bool live = (mb[T * 64 + nk * 16 + c] != 0);
#pragma unroll
      for (int r = 0; r < 4; ++r) {
        const float p = live ? __builtin_amdgcn_exp2f(fminf(SF[nk][r], 43.0f)) : 0.0f;
        const int qr = wv * 16 + g * 4 + r;
        *(short*)((char*)Ps + qr * 128 + (((nk * 16 + c) * 2) ^ ((qr & 7) << 4))) = f2b(p);
      }
    }
  };
  auto pv = [&](int T) {
    const char* vbase = (const char*)Vs + (T & 1) * 8192;
#pragma unroll
    for (int ks = 0; ks < 2; ++ks) {
      const int qr = wv * 16 + c;
      const bf16x8 pf =
          *(const bf16x8*)((const char*)Ps + qr * 128 + ((ks * 64 + g * 16) ^ ((qr & 7) << 4)));
      bf16x8 vf[4];
#pragma unroll
      for (int nd = 0; nd < 4; ++nd)
        vf[nd] = *(const bf16x8*)(vbase + (nd * 16 + c) * 128 + ((ks * 64 + g * 16) ^ xr));
#pragma unroll
      for (int nd = 0; nd < 4; ++nd)
        o[nd] = __builtin_amdgcn_mfma_f32_16x16x32_bf16(pf, vf[nd], o[nd], 0, 0, 0);
      ol = __builtin_amdgcn_mfma_f32_16x16x32_bf16(pf, onesf, ol, 0, 0, 0);
    }
  };

  // K slot byte-offsets: ks1 = slot of tile t+1 (QK source), ks2 = slot of t+2 (stage dest)
  uint32_t ks0 = 0, ks1 = 8192, ks2 = 16384;

  auto step = [&](int T, f32x4 (&SCUR)[4], f32x4 (&SNXT)[4]) {
    if (T + 2 < 32)
      gload_lds16(kh + (size_t)((T + 2) * 64 + srow) * 64 + slch * 8,
                  (char*)Ks + ks2 + wv * 1024);
    if (T + 1 < 32)
      gload_lds16(vth + (size_t)srow * 2048 + (T + 1) * 64 + slch * 8,
                  (char*)Vs + ((T + 1) & 1) * 8192 + wv * 1024);
    if (T + 1 < 32) qk((const char*)Ks + ks1, SNXT);  // MFMA ahead of exp VALU
    expph(T, SCUR);
    asm volatile("" ::: "memory");  // order P-writes before P-reads (wave-private)
    pv(T);
    __syncthreads();  // drains vmcnt(0): staged tiles landed; all waves done with V[T&1]
    const uint32_t tmp = ks0; ks0 = ks1; ks1 = ks2; ks2 = tmp;
  };

  // prologue: stage K0, V0, K1; compute QK(0)
  gload_lds16(kh + (size_t)srow * 64 + slch * 8, (char*)Ks + wv * 1024);
  gload_lds16(vth + (size_t)srow * 2048 + slch * 8, (char*)Vs + wv * 1024);
  gload_lds16(kh + (size_t)(64 + srow) * 64 + slch * 8, (char*)Ks + 8192 + wv * 1024);
  __syncthreads();
  qk((const char*)Ks, sfA);

  for (int tp = 0; tp < 16; ++tp) {  // 2 tiles per iteration (register double-buffer)
    step(tp * 2, sfA, sfB);
    step(tp * 2 + 1, sfB, sfA);
  }

  // normalize and store att[b*2048+q][h*64+d]
#pragma unroll
  for (int r = 0; r < 4; ++r) {
    const float lsum = __shfl(ol[r], ln & 48, 64);  // broadcast col-0 lane of the group
    const float inv = 1.0f / fmaxf(lsum, 1e-30f);
    const int qr = q0 + wv * 16 + g * 4 + r;
#pragma unroll
    for (int nd = 0; nd < 4; ++nd)
      att[(size_t)(b * 2048 + qr) * 1024 + h * 64 + nd * 16 + c] =
          __float2bfloat16(o[nd][r] * inv);
  }
}

extern "C" void kernel_launch(void* const* d_in, const int* in_sizes, int n_in,
                              void* d_out, int out_size, void* d_ws, size_t ws_size,
                              hipStream_t stream) {
  (void)in_sizes; (void)n_in; (void)out_size; (void)ws_size;
  const float* H    = (const float*)d_in[0];   // inputs are float32 per reference
  const int*   mask = (const int*)d_in[1];
  const float* Wq   = (const float*)d_in[2];
  const float* Wk   = (const float*)d_in[3];
  const float* Wv   = (const float*)d_in[4];
  const float* Wo   = (const float*)d_in[5];
  bf16* ws   = (bf16*)d_ws;
  bf16* wqT  = ws + OFF_WQT;
  bf16* wkT  = ws + OFF_WKT;
  bf16* wvT  = ws + OFF_WVT;
  bf16* woT  = ws + OFF_WOT;
  bf16* hb   = ws + OFF_HB;
  bf16* qws  = ws + OFF_Q;
  bf16* kws  = ws + OFF_K;
  bf16* vtws = ws + OFF_VT;
  bf16* attw = ws + OFF_ATT;

  // prep: z<4 weight transpose+cvt, z=4 H cvt
  prep_k<<<dim3(16, 16, 5), 256, 0, stream>>>(Wq, Wk, Wv, Wo, H, ws, hb);
  // fused QKV projection: z=0 Q (scaled), z=1 K, z=2 V (swapped-operand transposed write)
  gemm_k<0><<<dim3(8, 32, 3), 256, 0, stream>>>(hb, wqT, wkT, wvT, qws, kws, vtws);
  // attention: 128 q-rows per block, 8 waves, SW-pipelined QK-ahead
  attn_k<<<dim3(16, 32), 512, 0, stream>>>(qws, kws, vtws, mask, attw);
  // output projection (BM=128, BN=64 -> 512 blocks) -> float32 d_out
  gemm_k<2><<<dim3(16, 32), 256, 0, stream>>>(attw, woT, nullptr, nullptr, d_out, nullptr, nullptr);
}